// Round 24
// baseline (77.720 us; speedup 1.0000x reference)
//
#include <hip/hip_runtime.h>
#include <hip/hip_bf16.h>
#include <hip/hip_fp16.h>

// Problem constants (fixed by setup_inputs)
#define BATCH 16
#define NCH 3
#define H 512
#define W 512
#define HW (H * W)          // 262144 = 2^18
#define PAD 7
#define K 26                // int(0.0001 * 512 * 512)
#define NSUB 1024           // subs (4 rows x 64 cols = 256 px) per batch
#define NPAIR 32            // 2 maps x 16 batches
#define BK (BATCH * K)      // 416
#define CAP 32768           // candidate list capacity per pair
#define LDSCAP 6144         // merge LDS tile (48 KB)

#define TH1 32              // pool tile height
#define ROWS1 46            // TH1 + 14
#define SHP 68              // padded LDS stride for h-pool rows (64 used)
#define VCH 131072          // u32 per channel image in blocked fp16 Vmax layout

#define FINF __builtin_inff()

// native clang vector types (required by __builtin_nontemporal_store)
typedef unsigned uint4n __attribute__((ext_vector_type(4)));
typedef float float4n __attribute__((ext_vector_type(4)));

// monotone float->u32 key (order-preserving for all floats)
__device__ __forceinline__ unsigned mkey(float f) {
    unsigned u = __float_as_uint(f);
    unsigned m = (unsigned)(((int)u) >> 31) | 0x80000000u;
    return u ^ m;
}

__device__ __forceinline__ unsigned f2h2(float lo, float hi) {
    __half hl = __float2half(lo);
    __half hh = __float2half(hi);
    return (unsigned)*reinterpret_cast<unsigned short*>(&hl) |
           ((unsigned)*reinterpret_cast<unsigned short*>(&hh) << 16);
}
__device__ __forceinline__ float h2f(unsigned short s) {
    __half h = *reinterpret_cast<__half*>(&s);
    return __half2float(h);
}

__device__ __forceinline__ void nt_store4u(unsigned* p, unsigned a, unsigned b,
                                           unsigned c, unsigned d) {
    uint4n v = {a, b, c, d};
    __builtin_nontemporal_store(v, (uint4n*)p);
}
__device__ __forceinline__ void nt_store4f(float* p, float4 v) {
    float4n w = {v.x, v.y, v.z, v.w};
    __builtin_nontemporal_store(w, (float4n*)p);
}

__device__ __forceinline__ unsigned long long shfl_xor_u64(unsigned long long v, int m) {
    int lo = __shfl_xor((int)(unsigned)(v & 0xFFFFFFFFull), m);
    int hi = __shfl_xor((int)(unsigned)(v >> 32), m);
    return ((unsigned long long)(unsigned)hi << 32) | (unsigned)lo;
}

template <bool MX>
__device__ __forceinline__ float op(float a, float b) { return MX ? fmaxf(a, b) : fminf(a, b); }
template <bool MX>
__device__ __forceinline__ float4 op4(float4 a, float4 b) {
    return make_float4(op<MX>(a.x, b.x), op<MX>(a.y, b.y), op<MX>(a.z, b.z), op<MX>(a.w, b.w));
}

// horizontal 15-window pool of a 4-output group from 5 clamped-base float4s
template <bool MX>
__device__ __forceinline__ float4 hquad(float4 fA, float4 fB, float4 fC, float4 fD, float4 fE) {
    float4 m4 = op4<MX>(op4<MX>(fB, fC), fD);
    float tm = op<MX>(op<MX>(m4.x, m4.y), op<MX>(m4.z, m4.w));
    return make_float4(
        op<MX>(tm, op<MX>(fA.y, op<MX>(fA.z, fA.w))),
        op<MX>(tm, op<MX>(fA.z, op<MX>(fA.w, fE.x))),
        op<MX>(tm, op<MX>(fA.w, op<MX>(fE.x, fE.y))),
        op<MX>(tm, op<MX>(fE.x, op<MX>(fE.y, fE.z))));
}

// v-pool of 2 consecutive output rows from 16 LDS rows (14-row shared core)
template <bool MX>
__device__ __forceinline__ void vpool2(const float* __restrict__ sH, int vy, int vx,
                                       float4 o[2]) {
    const float* p0 = sH + vy * SHP + vx;
    float4 t4 = *(const float4*)(p0 + SHP);
#pragma unroll
    for (int j = 2; j <= 14; ++j) t4 = op4<MX>(t4, *(const float4*)(p0 + j * SHP));
    float4 r0 = *(const float4*)(p0);
    float4 r15 = *(const float4*)(p0 + 15 * SHP);
    o[0] = op4<MX>(r0, t4);
    o[1] = op4<MX>(t4, r15);
}

// ---------------------------------------------------------------------------
// K1: 64x32 tiles at 512 threads, 4 blocks/CU (LDS 25 KB <= 40 KB budget),
// grid 2048 = exactly 2 full rounds at 32 waves/CU. Halo fraction drops
// 14/30 -> 14/46: per-thread stage iterations 1.88 -> 1.44. Per channel:
// h-pool straight from global (5 clamped-base float4 loads per 4-output
// group == exact clamp-to-edge), max AND min from the same loads into two
// LDS buffers; x->out copy rides on the center float4. v-pool half-split:
// u<256 -> max map (blocked fp16 Vmax + bc subkeys), u>=256 -> min map (dc
// subkeys). Blocked Vmax: one 16B record (2 rows x 4 cols) per thread per
// channel; per-channel stride VCH = 128 tiles * 256 records * 4 u32 = 2^17.
// Write-once streams use nontemporal stores. Blocks 0..47 zero nCand/A2sum.
__global__ __launch_bounds__(512, 4) void pool_maps_kernel(
    const float* __restrict__ x, unsigned* __restrict__ vmaxb,
    unsigned* __restrict__ dcK, unsigned* __restrict__ bcK,
    unsigned* __restrict__ subkey, float* __restrict__ out,
    int* __restrict__ nCand, float* __restrict__ A2sum) {
    __shared__ __align__(16) float sHmax[ROWS1 * SHP];
    __shared__ __align__(16) float sHmin[ROWS1 * SHP];
    int blk = blockIdx.x;
    if (threadIdx.x == 0) {
        if (blk < NPAIR) nCand[blk] = 0;
        if (blk < BATCH * NCH) A2sum[blk] = 0.0f;
    }
    int b = blk >> 7;
    int tile = blk & 127;          // 8 cols x 16 rows of 64x32 tiles
    int tx0 = (tile & 7) << 6;
    int ty0 = (tile >> 3) << 5;
    int u = threadIdx.x;
    int half = u >> 8;      // 0: max map (bc + Vmax), 1: min map (dc)
    int v = u & 255;
    int rg = v >> 4;        // 0..15 row-pairs
    int cg = v & 15;
    int vx = cg << 2;
    int vy = rg << 1;       // 0,2,..,30
    float4 acc[2];
    float ainit = half ? FINF : -FINF;
    acc[0] = acc[1] = make_float4(ainit, ainit, ainit, ainit);

    for (int c = 0; c < NCH; ++c) {
        const float* xp = x + (((size_t)(b * NCH + c)) << 18);
        float* outp = out + (((size_t)(b * 4 + c)) << 18);
        for (int it = u; it < ROWS1 * 16; it += 512) {
            int r = it >> 4;
            int x0 = (it & 15) << 2;
            int gy = ty0 - PAD + r;
            gy = gy < 0 ? 0 : (gy > H - 1 ? H - 1 : gy);
            const float* rowp = xp + (gy << 9);
            int gx0 = tx0 + x0;
            int aB = gx0 - 8; aB = aB < 0 ? 0 : aB;
            int bB = gx0 - 4; bB = bB < 0 ? 0 : bB;
            int dB = gx0 + 4; dB = dB > W - 4 ? W - 4 : dB;
            int eB = gx0 + 8; eB = eB > W - 4 ? W - 4 : eB;
            float4 fA = *(const float4*)(rowp + aB);
            float4 fB = *(const float4*)(rowp + bB);
            float4 fC = *(const float4*)(rowp + gx0);
            float4 fD = *(const float4*)(rowp + dB);
            float4 fE = *(const float4*)(rowp + eB);
            if (r >= PAD && r < PAD + TH1)
                nt_store4f(&outp[((ty0 + r - PAD) << 9) + gx0], fC);
            *(float4*)&sHmax[r * SHP + x0] = hquad<true>(fA, fB, fC, fD, fE);
            *(float4*)&sHmin[r * SHP + x0] = hquad<false>(fA, fB, fC, fD, fE);
        }
        __syncthreads();
        if (half == 0) {
            float4 o[2];
            vpool2<true>(sHmax, vy, vx, o);
            unsigned* vp = vmaxb + (size_t)(b * NCH + c) * VCH + tile * 1024 + v * 4;
            nt_store4u(vp, f2h2(o[0].x, o[0].y), f2h2(o[0].z, o[0].w),
                       f2h2(o[1].x, o[1].y), f2h2(o[1].z, o[1].w));
            acc[0] = op4<true>(acc[0], o[0]);
            acc[1] = op4<true>(acc[1], o[1]);
        } else {
            float4 o[2];
            vpool2<false>(sHmin, vy, vx, o);
            acc[0] = op4<false>(acc[0], o[0]);
            acc[1] = op4<false>(acc[1], o[1]);
        }
        __syncthreads();
    }
    // ---- per-pixel key maps + per-sub (4 rows x 64 cols) key maxima ----
    unsigned gb = ((unsigned)b << 18) + ((ty0 + vy) << 9) + tx0 + vx;
    if (half == 0) {
        nt_store4u(&bcK[gb], ~mkey(acc[0].x), ~mkey(acc[0].y), ~mkey(acc[0].z), ~mkey(acc[0].w));
        nt_store4u(&bcK[gb + 512], ~mkey(acc[1].x), ~mkey(acc[1].y), ~mkey(acc[1].z), ~mkey(acc[1].w));
        float mn = fminf(fminf(fminf(acc[0].x, acc[0].y), fminf(acc[0].z, acc[0].w)),
                         fminf(fminf(acc[1].x, acc[1].y), fminf(acc[1].z, acc[1].w)));
#pragma unroll
        for (int s = 1; s < 32; s <<= 1) mn = fminf(mn, __shfl_xor(mn, s));
        if ((v & 31) == 0)
            subkey[(BATCH + b) * NSUB + tile * 8 + (v >> 5)] = ~mkey(mn);
    } else {
        nt_store4u(&dcK[gb], mkey(acc[0].x), mkey(acc[0].y), mkey(acc[0].z), mkey(acc[0].w));
        nt_store4u(&dcK[gb + 512], mkey(acc[1].x), mkey(acc[1].y), mkey(acc[1].z), mkey(acc[1].w));
        float mx = fmaxf(fmaxf(fmaxf(acc[0].x, acc[0].y), fmaxf(acc[0].z, acc[0].w)),
                         fmaxf(fmaxf(acc[1].x, acc[1].y), fmaxf(acc[1].z, acc[1].w)));
#pragma unroll
        for (int s = 1; s < 32; s <<= 1) mx = fmaxf(mx, __shfl_xor(mx, s));
        if ((v & 31) == 0)
            subkey[b * NSUB + tile * 8 + (v >> 5)] = mkey(mx);
    }
}

// ---------------------------------------------------------------------------
// K2 (r20-proven): fused tau + gather, 256 blocks (8/pair), no cross-block
// sync, no dependent shuffle chains. Wave 0: tau by 32-step binary search on
// the key value (count via 16 independent ballot+popcount per step); result
// = the 26th-largest subkey — theorem: {key >= tau} contains the
// lexicographic top-26. Ballot-compact qualifying subs; then each WAVE
// gathers whole subs independently (4 px/lane) with one atomicAdd per sub.
// Sub decode: tile (64x32) has 8 subs of 4 rows.
__global__ __launch_bounds__(256) void taugather_kernel(
    const unsigned* __restrict__ keys, const unsigned* __restrict__ subkey,
    int* __restrict__ nCand, unsigned long long* __restrict__ cand) {
    int blk = blockIdx.x;
    int pair = blk >> 3;
    int bslot = blk & 7;
    int t = threadIdx.x;
    int wv = t >> 6, lane = t & 63;
    __shared__ int sList[NSUB];
    __shared__ unsigned sTau;
    __shared__ int sN;
    if (wv == 0) {
        const unsigned* sk = subkey + (size_t)pair * NSUB + lane * 16;
        unsigned ko[16];
        *(uint4*)&ko[0] = *(const uint4*)&sk[0];
        *(uint4*)&ko[4] = *(const uint4*)&sk[4];
        *(uint4*)&ko[8] = *(const uint4*)&sk[8];
        *(uint4*)&ko[12] = *(const uint4*)&sk[12];
        unsigned tv = 0;
#pragma unroll
        for (int bit = 31; bit >= 0; --bit) {
            unsigned cnd = tv | (1u << bit);
            int cnt = 0;
#pragma unroll
            for (int j = 0; j < 16; ++j)
                cnt += (int)__popcll(__ballot(ko[j] >= cnd));
            if (cnt >= K) tv = cnd;
        }
        unsigned long long lt = (1ull << lane) - 1ull;
        int base = 0;
#pragma unroll
        for (int j = 0; j < 16; ++j) {
            bool qq = ko[j] >= tv;
            unsigned long long mk = __ballot(qq);
            if (qq) sList[base + (int)__popcll(mk & lt)] = lane * 16 + j;
            base += (int)__popcll(mk);
        }
        if (lane == 0) { sTau = tv; sN = base; }
    }
    __syncthreads();
    unsigned tv = sTau;
    int n = sN;
    const unsigned* kp = keys + ((size_t)pair << 18);
    unsigned long long* cp = cand + (size_t)pair * CAP;
    unsigned long long lt = (1ull << lane) - 1ull;
    for (int si = bslot * 4 + wv; si < n; si += 32) {
        int sub = sList[si];
        int tile = sub >> 3, sr = sub & 7;
        int xs = (tile & 7) << 6;
        int ys = ((tile >> 3) << 5) + (sr << 2);
        int p0 = (ys << 9) + xs + lane;
        unsigned k0 = kp[p0];
        unsigned k1 = kp[p0 + 512];
        unsigned k2 = kp[p0 + 1024];
        unsigned k3 = kp[p0 + 1536];
        bool q0 = k0 >= tv, q1 = k1 >= tv, q2 = k2 >= tv, q3 = k3 >= tv;
        unsigned long long m0 = __ballot(q0);
        unsigned long long m1 = __ballot(q1);
        unsigned long long m2 = __ballot(q2);
        unsigned long long m3 = __ballot(q3);
        int c0 = (int)__popcll(m0), c1 = (int)__popcll(m1);
        int c2 = (int)__popcll(m2), c3 = (int)__popcll(m3);
        int tot = c0 + c1 + c2 + c3;
        if (tot == 0) continue;
        int base = 0;
        if (lane == 0) base = atomicAdd(&nCand[pair], tot);
        base = __shfl(base, 0);
        if (q0) {
            int slot = base + (int)__popcll(m0 & lt);
            if (slot < CAP) cp[slot] = ((unsigned long long)k0 << 32) | (unsigned)(0x7FFFFFFF - p0);
        }
        if (q1) {
            int slot = base + c0 + (int)__popcll(m1 & lt);
            if (slot < CAP) cp[slot] = ((unsigned long long)k1 << 32) | (unsigned)(0x7FFFFFFF - (p0 + 512));
        }
        if (q2) {
            int slot = base + c0 + c1 + (int)__popcll(m2 & lt);
            if (slot < CAP) cp[slot] = ((unsigned long long)k2 << 32) | (unsigned)(0x7FFFFFFF - (p0 + 1024));
        }
        if (q3) {
            int slot = base + c0 + c1 + c2 + (int)__popcll(m3 & lt);
            if (slot < CAP) cp[slot] = ((unsigned long long)k3 << 32) | (unsigned)(0x7FFFFFFF - (p0 + 1536));
        }
    }
}

// ---------------------------------------------------------------------------
// K3 (r18/r20-proven): per-pair merge of nCand candidates -> global top-26.
// map0 (dc): A1 (argmax of per-pixel channel max, first occurrence).
// map1 (bc): partial A2 sums — this block's 26 indices contribute to EVERY
// batch's A2 (faithful to the reference's batch-mixing bug): 48 (batch,ch)
// serial 26-element sums + ONE atomicAdd each (768 atomics total).
__global__ __launch_bounds__(256) void merge_kernel(
    const unsigned long long* __restrict__ cand, const int* __restrict__ nCand,
    const float* __restrict__ img, float* __restrict__ A1, float* __restrict__ A2sum) {
    int pair = blockIdx.x;
    int map = pair >> 4, b = pair & 15;
    int t = threadIdx.x;
    int wv = t >> 6, lane = t & 63;
    int n = nCand[pair];
    n = n < CAP ? n : CAP;
    const unsigned long long* cp = cand + (size_t)pair * CAP;
    __shared__ unsigned long long sC[LDSCAP];
    __shared__ unsigned long long sB[4];
    __shared__ unsigned long long sWin[K];
    __shared__ float sM[K];
    __shared__ int sIdx[K];
    int ntile = (n + LDSCAP - 1) / LDSCAP;
    unsigned long long kc = 0;
    for (int tl = 0; tl < ntile; ++tl) {
        int lo = tl * LDSCAP;
        int m = n - lo; m = m > LDSCAP ? LDSCAP : m;
        for (int i = t; i < m; i += 256) sC[i] = cp[lo + i];
        if (tl > 0) kc = (t < K) ? sWin[t] : 0ull;
        __syncthreads();
        unsigned long long lm = 0;
        int slot = -1;
        for (int i = t; i < m; i += 256) {
            unsigned long long v = sC[i];
            if (v > lm) { lm = v; slot = i; }
        }
        for (int r = 0; r < K; ++r) {
            unsigned long long mm = lm > kc ? lm : kc;
#pragma unroll
            for (int s = 1; s < 64; s <<= 1) {
                unsigned long long o = shfl_xor_u64(mm, s);
                mm = o > mm ? o : mm;
            }
            if (lane == 0) sB[wv] = mm;
            __syncthreads();
            unsigned long long wb = sB[0];
            if (sB[1] > wb) wb = sB[1];
            if (sB[2] > wb) wb = sB[2];
            if (sB[3] > wb) wb = sB[3];
            if (t == 0) sWin[r] = wb;
            if (wb == lm && slot >= 0) {    // owner: remove + rescan own slice
                sC[slot] = 0ull;
                lm = 0; slot = -1;
                for (int i = t; i < m; i += 256) {
                    unsigned long long v = sC[i];
                    if (v > lm) { lm = v; slot = i; }
                }
            }
            if (wb == kc) kc = 0ull;
            __syncthreads();
        }
    }
    if (t < K) sIdx[t] = 0x7FFFFFFF - (int)(unsigned)(sWin[t] & 0xFFFFFFFFull);
    __syncthreads();
    if (map == 0) {
        if (t < K) {
            int p = sIdx[t];
            float m = img[(((size_t)(b * NCH + 0)) << 18) + p];
            m = fmaxf(m, img[(((size_t)(b * NCH + 1)) << 18) + p]);
            m = fmaxf(m, img[(((size_t)(b * NCH + 2)) << 18) + p]);
            sM[t] = m;
        }
        __syncthreads();
        if (t == 0) {
            float bm = -FINF;
            int bj = 0;
            for (int j = 0; j < K; ++j)
                if (sM[j] > bm) { bm = sM[j]; bj = j; }   // strict > = first occurrence
            int p = sIdx[bj];
#pragma unroll
            for (int c = 0; c < NCH; ++c)
                A1[b * NCH + c] = img[(((size_t)(b * NCH + c)) << 18) + p];
        }
    } else {
        if (t < BATCH * NCH) {
            const float* xp = img + ((size_t)t << 18);
            float s = 0.0f;
            for (int j = 0; j < K; ++j) s += xp[sIdx[j]];
            atomicAdd(&A2sum[t], s);
        }
    }
}

__device__ __forceinline__ float tvh(unsigned h, bool hi, float r) {
    unsigned short s = hi ? (unsigned short)(h >> 16) : (unsigned short)(h & 0xFFFF);
    return fmaf(-h2f(s), r, r);
}

// ---------------------------------------------------------------------------
// K4: t = 1 - 0.95 * min_c (1 - M_c)*r_c from the BLOCKED fp16 Vmax layout
// (128 tiles x 256 records per channel): per thread one (tile, v) record =
// 2 rows x 4 cols; 3x16B loads, 2x16B stores. r_c from A1/A2sum inline.
__global__ __launch_bounds__(256) void final_t_kernel(
    const unsigned* __restrict__ vmaxb, const float* __restrict__ A1,
    const float* __restrict__ A2sum, float* __restrict__ out) {
    int g = blockIdx.x * 256 + threadIdx.x;   // 524288 threads
    int b = g >> 15;                           // 32768 records per batch
    int rem = g & 32767;
    int tile = rem >> 8;                       // 0..127
    int v = rem & 255;
    const float invBK = 1.0f / (float)BK;
    float A0 = 0.75f * A1[b * NCH + 0] + 0.25f * (A2sum[b * NCH + 0] * invBK);
    float Ab = 0.75f * A1[b * NCH + 1] + 0.25f * (A2sum[b * NCH + 1] * invBK);
    float Ac = 0.75f * A1[b * NCH + 2] + 0.25f * (A2sum[b * NCH + 2] * invBK);
    float r0 = 1.0f / ((1.0f - A0) + 1e-6f);
    float r1 = 1.0f / ((1.0f - Ab) + 1e-6f);
    float r2 = 1.0f / ((1.0f - Ac) + 1e-6f);
    size_t rbase = (size_t)tile * 1024 + v * 4;
    uint4 c0 = *(const uint4*)(vmaxb + (size_t)(b * NCH + 0) * VCH + rbase);
    uint4 c1 = *(const uint4*)(vmaxb + (size_t)(b * NCH + 1) * VCH + rbase);
    uint4 c2 = *(const uint4*)(vmaxb + (size_t)(b * NCH + 2) * VCH + rbase);
    float4 ta, tb;
    ta.x = 1.0f - 0.95f * fminf(fminf(tvh(c0.x, false, r0), tvh(c1.x, false, r1)), tvh(c2.x, false, r2));
    ta.y = 1.0f - 0.95f * fminf(fminf(tvh(c0.x, true, r0), tvh(c1.x, true, r1)), tvh(c2.x, true, r2));
    ta.z = 1.0f - 0.95f * fminf(fminf(tvh(c0.y, false, r0), tvh(c1.y, false, r1)), tvh(c2.y, false, r2));
    ta.w = 1.0f - 0.95f * fminf(fminf(tvh(c0.y, true, r0), tvh(c1.y, true, r1)), tvh(c2.y, true, r2));
    tb.x = 1.0f - 0.95f * fminf(fminf(tvh(c0.z, false, r0), tvh(c1.z, false, r1)), tvh(c2.z, false, r2));
    tb.y = 1.0f - 0.95f * fminf(fminf(tvh(c0.z, true, r0), tvh(c1.z, true, r1)), tvh(c2.z, true, r2));
    tb.z = 1.0f - 0.95f * fminf(fminf(tvh(c0.w, false, r0), tvh(c1.w, false, r1)), tvh(c2.w, false, r2));
    tb.w = 1.0f - 0.95f * fminf(fminf(tvh(c0.w, true, r0), tvh(c1.w, true, r1)), tvh(c2.w, true, r2));
    int tx0 = (tile & 7) << 6;
    int ty0 = (tile >> 3) << 5;
    int rg = v >> 4, cg = v & 15;
    int row0 = ty0 + (rg << 1);
    int col = tx0 + (cg << 2);
    float* op3 = out + (((size_t)(b * 4 + 3)) << 18);
    *(float4*)&op3[(row0 << 9) + col] = ta;
    *(float4*)&op3[((row0 + 1) << 9) + col] = tb;
}

// ---------------------------------------------------------------------------
extern "C" void kernel_launch(void* const* d_in, const int* in_sizes, int n_in,
                              void* d_out, int out_size, void* d_ws, size_t ws_size,
                              hipStream_t stream) {
    const float* x = (const float*)d_in[0];
    float* out = (float*)d_out;

    const size_t nPix = (size_t)BATCH * HW;      // 4,194,304

    unsigned long long* cand = (unsigned long long*)d_ws;        // 8 MB
    unsigned* dcK = (unsigned*)(cand + (size_t)NPAIR * CAP);     // 16 MB
    unsigned* bcK = dcK + nPix;                                  // 16 MB (contiguous with dcK)
    unsigned* vmaxb = bcK + nPix;                                // 24 MB blocked fp16 (u32 view)
    unsigned* subkey = vmaxb + (size_t)BATCH * NCH * VCH;        // [2][16][1024]
    int* nCand = (int*)(subkey + (size_t)NPAIR * NSUB);
    float* A1 = (float*)(nCand + NPAIR);
    float* A2sum = A1 + BATCH * NCH;

    pool_maps_kernel<<<BATCH * 128, 512, 0, stream>>>(x, vmaxb, dcK, bcK, subkey, out,
                                                      nCand, A2sum);
    taugather_kernel<<<NPAIR * 8, 256, 0, stream>>>(dcK, subkey, nCand, cand);
    merge_kernel<<<NPAIR, 256, 0, stream>>>(cand, nCand, x, A1, A2sum);
    final_t_kernel<<<2048, 256, 0, stream>>>(vmaxb, A1, A2sum, out);
}

// Round 25
// 75.465 us; speedup vs baseline: 1.0299x; 1.0299x over previous
//
#include <hip/hip_runtime.h>
#include <hip/hip_bf16.h>
#include <hip/hip_fp16.h>

// Problem constants (fixed by setup_inputs)
#define BATCH 16
#define NCH 3
#define H 512
#define W 512
#define HW (H * W)          // 262144 = 2^18
#define PAD 7
#define K 26                // int(0.0001 * 512 * 512)
#define NSUB 1024           // subs (4 rows x 64 cols = 256 px) per batch
#define NPAIR 32            // 2 maps x 16 batches
#define BK (BATCH * K)      // 416
#define LDSCAP 6144         // candidate LDS capacity (48 KB)
#define CSUBS 24            // fallback chunk: 24 subs * 256 px = 6144

#define TH1 32              // pool tile height
#define ROWS1 46            // TH1 + 14
#define SHP 68              // padded LDS stride for h-pool rows (64 used)
#define VCH 131072          // u32 per channel image in blocked fp16 Vmax layout

#define FINF __builtin_inff()

// native clang vector types (required by __builtin_nontemporal_store)
typedef unsigned uint4n __attribute__((ext_vector_type(4)));
typedef float float4n __attribute__((ext_vector_type(4)));

// monotone float->u32 key (order-preserving for all floats)
__device__ __forceinline__ unsigned mkey(float f) {
    unsigned u = __float_as_uint(f);
    unsigned m = (unsigned)(((int)u) >> 31) | 0x80000000u;
    return u ^ m;
}

__device__ __forceinline__ unsigned f2h2(float lo, float hi) {
    __half hl = __float2half(lo);
    __half hh = __float2half(hi);
    return (unsigned)*reinterpret_cast<unsigned short*>(&hl) |
           ((unsigned)*reinterpret_cast<unsigned short*>(&hh) << 16);
}
__device__ __forceinline__ float h2f(unsigned short s) {
    __half h = *reinterpret_cast<__half*>(&s);
    return __half2float(h);
}

__device__ __forceinline__ void nt_store4u(unsigned* p, unsigned a, unsigned b,
                                           unsigned c, unsigned d) {
    uint4n v = {a, b, c, d};
    __builtin_nontemporal_store(v, (uint4n*)p);
}
__device__ __forceinline__ void nt_store4f(float* p, float4 v) {
    float4n w = {v.x, v.y, v.z, v.w};
    __builtin_nontemporal_store(w, (float4n*)p);
}

__device__ __forceinline__ unsigned long long shfl_xor_u64(unsigned long long v, int m) {
    int lo = __shfl_xor((int)(unsigned)(v & 0xFFFFFFFFull), m);
    int hi = __shfl_xor((int)(unsigned)(v >> 32), m);
    return ((unsigned long long)(unsigned)hi << 32) | (unsigned)lo;
}

template <bool MX>
__device__ __forceinline__ float op(float a, float b) { return MX ? fmaxf(a, b) : fminf(a, b); }
template <bool MX>
__device__ __forceinline__ float4 op4(float4 a, float4 b) {
    return make_float4(op<MX>(a.x, b.x), op<MX>(a.y, b.y), op<MX>(a.z, b.z), op<MX>(a.w, b.w));
}

// horizontal 15-window pool of a 4-output group from 5 clamped-base float4s
template <bool MX>
__device__ __forceinline__ float4 hquad(float4 fA, float4 fB, float4 fC, float4 fD, float4 fE) {
    float4 m4 = op4<MX>(op4<MX>(fB, fC), fD);
    float tm = op<MX>(op<MX>(m4.x, m4.y), op<MX>(m4.z, m4.w));
    return make_float4(
        op<MX>(tm, op<MX>(fA.y, op<MX>(fA.z, fA.w))),
        op<MX>(tm, op<MX>(fA.z, op<MX>(fA.w, fE.x))),
        op<MX>(tm, op<MX>(fA.w, op<MX>(fE.x, fE.y))),
        op<MX>(tm, op<MX>(fE.x, op<MX>(fE.y, fE.z))));
}

// v-pool of 2 consecutive output rows from 16 LDS rows (14-row shared core)
template <bool MX>
__device__ __forceinline__ void vpool2(const float* __restrict__ sH, int vy, int vx,
                                       float4 o[2]) {
    const float* p0 = sH + vy * SHP + vx;
    float4 t4 = *(const float4*)(p0 + SHP);
#pragma unroll
    for (int j = 2; j <= 14; ++j) t4 = op4<MX>(t4, *(const float4*)(p0 + j * SHP));
    float4 r0 = *(const float4*)(p0);
    float4 r15 = *(const float4*)(p0 + 15 * SHP);
    o[0] = op4<MX>(r0, t4);
    o[1] = op4<MX>(t4, r15);
}

// ---------------------------------------------------------------------------
// K1 (r24-proven): 64x32 tiles at 512 threads, 4 blocks/CU, grid 2048 =
// exactly 2 full rounds at 32 waves/CU. Per channel: h-pool straight from
// global (5 clamped-base float4 loads per 4-output group == exact
// clamp-to-edge), max AND min from the same loads into two LDS buffers;
// x->out copy rides on the center float4. v-pool half-split: u<256 -> max map
// (blocked fp16 Vmax + bc subkeys), u>=256 -> min map (dc subkeys).
// Blocked Vmax: one 16B record (2 rows x 4 cols) per thread per channel;
// per-channel stride VCH = 2^17 u32. Write-once streams use nontemporal
// stores. Blocks 0..47 zero A2sum.
__global__ __launch_bounds__(512, 4) void pool_maps_kernel(
    const float* __restrict__ x, unsigned* __restrict__ vmaxb,
    unsigned* __restrict__ dcK, unsigned* __restrict__ bcK,
    unsigned* __restrict__ subkey, float* __restrict__ out,
    float* __restrict__ A2sum) {
    __shared__ __align__(16) float sHmax[ROWS1 * SHP];
    __shared__ __align__(16) float sHmin[ROWS1 * SHP];
    int blk = blockIdx.x;
    if (threadIdx.x == 0 && blk < BATCH * NCH) A2sum[blk] = 0.0f;
    int b = blk >> 7;
    int tile = blk & 127;          // 8 cols x 16 rows of 64x32 tiles
    int tx0 = (tile & 7) << 6;
    int ty0 = (tile >> 3) << 5;
    int u = threadIdx.x;
    int half = u >> 8;      // 0: max map (bc + Vmax), 1: min map (dc)
    int v = u & 255;
    int rg = v >> 4;        // 0..15 row-pairs
    int cg = v & 15;
    int vx = cg << 2;
    int vy = rg << 1;       // 0,2,..,30
    float4 acc[2];
    float ainit = half ? FINF : -FINF;
    acc[0] = acc[1] = make_float4(ainit, ainit, ainit, ainit);

    for (int c = 0; c < NCH; ++c) {
        const float* xp = x + (((size_t)(b * NCH + c)) << 18);
        float* outp = out + (((size_t)(b * 4 + c)) << 18);
        for (int it = u; it < ROWS1 * 16; it += 512) {
            int r = it >> 4;
            int x0 = (it & 15) << 2;
            int gy = ty0 - PAD + r;
            gy = gy < 0 ? 0 : (gy > H - 1 ? H - 1 : gy);
            const float* rowp = xp + (gy << 9);
            int gx0 = tx0 + x0;
            int aB = gx0 - 8; aB = aB < 0 ? 0 : aB;
            int bB = gx0 - 4; bB = bB < 0 ? 0 : bB;
            int dB = gx0 + 4; dB = dB > W - 4 ? W - 4 : dB;
            int eB = gx0 + 8; eB = eB > W - 4 ? W - 4 : eB;
            float4 fA = *(const float4*)(rowp + aB);
            float4 fB = *(const float4*)(rowp + bB);
            float4 fC = *(const float4*)(rowp + gx0);
            float4 fD = *(const float4*)(rowp + dB);
            float4 fE = *(const float4*)(rowp + eB);
            if (r >= PAD && r < PAD + TH1)
                nt_store4f(&outp[((ty0 + r - PAD) << 9) + gx0], fC);
            *(float4*)&sHmax[r * SHP + x0] = hquad<true>(fA, fB, fC, fD, fE);
            *(float4*)&sHmin[r * SHP + x0] = hquad<false>(fA, fB, fC, fD, fE);
        }
        __syncthreads();
        if (half == 0) {
            float4 o[2];
            vpool2<true>(sHmax, vy, vx, o);
            unsigned* vp = vmaxb + (size_t)(b * NCH + c) * VCH + tile * 1024 + v * 4;
            nt_store4u(vp, f2h2(o[0].x, o[0].y), f2h2(o[0].z, o[0].w),
                       f2h2(o[1].x, o[1].y), f2h2(o[1].z, o[1].w));
            acc[0] = op4<true>(acc[0], o[0]);
            acc[1] = op4<true>(acc[1], o[1]);
        } else {
            float4 o[2];
            vpool2<false>(sHmin, vy, vx, o);
            acc[0] = op4<false>(acc[0], o[0]);
            acc[1] = op4<false>(acc[1], o[1]);
        }
        __syncthreads();
    }
    // ---- per-pixel key maps + per-sub (4 rows x 64 cols) key maxima ----
    unsigned gb = ((unsigned)b << 18) + ((ty0 + vy) << 9) + tx0 + vx;
    if (half == 0) {
        nt_store4u(&bcK[gb], ~mkey(acc[0].x), ~mkey(acc[0].y), ~mkey(acc[0].z), ~mkey(acc[0].w));
        nt_store4u(&bcK[gb + 512], ~mkey(acc[1].x), ~mkey(acc[1].y), ~mkey(acc[1].z), ~mkey(acc[1].w));
        float mn = fminf(fminf(fminf(acc[0].x, acc[0].y), fminf(acc[0].z, acc[0].w)),
                         fminf(fminf(acc[1].x, acc[1].y), fminf(acc[1].z, acc[1].w)));
#pragma unroll
        for (int s = 1; s < 32; s <<= 1) mn = fminf(mn, __shfl_xor(mn, s));
        if ((v & 31) == 0)
            subkey[(BATCH + b) * NSUB + tile * 8 + (v >> 5)] = ~mkey(mn);
    } else {
        nt_store4u(&dcK[gb], mkey(acc[0].x), mkey(acc[0].y), mkey(acc[0].z), mkey(acc[0].w));
        nt_store4u(&dcK[gb + 512], mkey(acc[1].x), mkey(acc[1].y), mkey(acc[1].z), mkey(acc[1].w));
        float mx = fmaxf(fmaxf(fmaxf(acc[0].x, acc[0].y), fmaxf(acc[0].z, acc[0].w)),
                         fmaxf(fmaxf(acc[1].x, acc[1].y), fmaxf(acc[1].z, acc[1].w)));
#pragma unroll
        for (int s = 1; s < 32; s <<= 1) mx = fmaxf(mx, __shfl_xor(mx, s));
        if ((v & 31) == 0)
            subkey[b * NSUB + tile * 8 + (v >> 5)] = mkey(mx);
    }
}

// ---------------------------------------------------------------------------
// merge body (r18/r20-proven): 26 block-max rounds with cached per-thread
// slice max over total LDS candidates, folding carry kc; winners into sWin.
__device__ __forceinline__ void merge_rounds(
    unsigned long long* sC, unsigned long long* sB, unsigned long long* sWin,
    int total, unsigned long long kc, int t, int wv, int lane) {
    unsigned long long lm = 0;
    int slot = -1;
    for (int i = t; i < total; i += 256) {
        unsigned long long v = sC[i];
        if (v > lm) { lm = v; slot = i; }
    }
    for (int r = 0; r < K; ++r) {
        unsigned long long mm = lm > kc ? lm : kc;
#pragma unroll
        for (int s = 1; s < 64; s <<= 1) {
            unsigned long long o = shfl_xor_u64(mm, s);
            mm = o > mm ? o : mm;
        }
        if (lane == 0) sB[wv] = mm;
        __syncthreads();
        unsigned long long wb = sB[0];
        if (sB[1] > wb) wb = sB[1];
        if (sB[2] > wb) wb = sB[2];
        if (sB[3] > wb) wb = sB[3];
        if (t == 0) sWin[r] = wb;
        if (wb == lm && slot >= 0) {        // owner: remove + rescan own slice
            sC[slot] = 0ull;
            lm = 0; slot = -1;
            for (int i = t; i < total; i += 256) {
                unsigned long long v = sC[i];
                if (v > lm) { lm = v; slot = i; }
            }
        }
        if (wb == kc) kc = 0ull;
        __syncthreads();
    }
}

// ---------------------------------------------------------------------------
// K2: FUSED tau + gather + merge, ONE block per (map,batch) pair, no
// cross-block communication at all (each pair's candidates are produced and
// consumed by the same block, in LDS). Wave 0: tau by 32-step binary search
// (16 independent ballot+popcount per step) = 26th-largest subkey; theorem:
// {key >= tau} contains the lexicographic top-26. Ballot-compact qualifying
// subs. Gather: wave-per-sub (4 px/lane), qualifying candidates appended to
// LDS via one LDS atomicAdd per sub. Common case total <= 6144 -> ONE
// 26-round merge. Rare overflow (deterministic flag) -> exact re-gather in
// 24-sub chunks with carry. Epilogue: map0 -> A1 (argmax of channel max,
// first occurrence); map1 -> partial A2 sums for EVERY batch (faithful to
// the reference's batch-mixing bug), one global atomicAdd per (batch,ch).
__global__ __launch_bounds__(256) void select_kernel(
    const unsigned* __restrict__ keys, const unsigned* __restrict__ subkey,
    const float* __restrict__ img, float* __restrict__ A1, float* __restrict__ A2sum) {
    int pair = blockIdx.x;
    int map = pair >> 4, b = pair & 15;
    int t = threadIdx.x;
    int wv = t >> 6, lane = t & 63;
    __shared__ int sList[NSUB];
    __shared__ __align__(16) unsigned long long sC[LDSCAP];
    __shared__ unsigned long long sB[4];
    __shared__ unsigned long long sWin[K];
    __shared__ float sM[K];
    __shared__ int sIdx[K];
    __shared__ unsigned sTau;
    __shared__ int sN;
    __shared__ int sCnt;
    __shared__ int sOver;

    // ---- Phase A: tau (binary search) + compact (wave 0; r20-proven) ----
    if (wv == 0) {
        const unsigned* sk = subkey + (size_t)pair * NSUB + lane * 16;
        unsigned ko[16];
        *(uint4*)&ko[0] = *(const uint4*)&sk[0];
        *(uint4*)&ko[4] = *(const uint4*)&sk[4];
        *(uint4*)&ko[8] = *(const uint4*)&sk[8];
        *(uint4*)&ko[12] = *(const uint4*)&sk[12];
        unsigned tv = 0;
#pragma unroll
        for (int bit = 31; bit >= 0; --bit) {
            unsigned cnd = tv | (1u << bit);
            int cnt = 0;
#pragma unroll
            for (int j = 0; j < 16; ++j)
                cnt += (int)__popcll(__ballot(ko[j] >= cnd));
            if (cnt >= K) tv = cnd;
        }
        unsigned long long lt = (1ull << lane) - 1ull;
        int base = 0;
#pragma unroll
        for (int j = 0; j < 16; ++j) {
            bool qq = ko[j] >= tv;
            unsigned long long mk = __ballot(qq);
            if (qq) sList[base + (int)__popcll(mk & lt)] = lane * 16 + j;
            base += (int)__popcll(mk);
        }
        if (lane == 0) { sTau = tv; sN = base; }
    }
    if (t == 0) { sCnt = 0; sOver = 0; }
    __syncthreads();
    unsigned tv = sTau;
    int n = sN;
    const unsigned* kp = keys + ((size_t)pair << 18);
    unsigned long long lt = (1ull << lane) - 1ull;

    // ---- Phase B: optimistic gather of ALL subs into LDS ----
    for (int si = wv; si < n; si += 4) {
        int sub = sList[si];
        int tile = sub >> 3, sr = sub & 7;
        int xs = (tile & 7) << 6;
        int ys = ((tile >> 3) << 5) + (sr << 2);
        int p0 = (ys << 9) + xs + lane;
        unsigned k0 = kp[p0];
        unsigned k1 = kp[p0 + 512];
        unsigned k2 = kp[p0 + 1024];
        unsigned k3 = kp[p0 + 1536];
        bool q0 = k0 >= tv, q1 = k1 >= tv, q2 = k2 >= tv, q3 = k3 >= tv;
        unsigned long long m0 = __ballot(q0), m1 = __ballot(q1);
        unsigned long long m2 = __ballot(q2), m3 = __ballot(q3);
        int c0 = (int)__popcll(m0), c1 = (int)__popcll(m1);
        int c2 = (int)__popcll(m2), c3 = (int)__popcll(m3);
        int tot = c0 + c1 + c2 + c3;
        if (tot == 0) continue;
        int base = 0;
        if (lane == 0) {
            base = atomicAdd(&sCnt, tot);
            if (base + tot > LDSCAP) sOver = 1;
        }
        base = __shfl(base, 0);
        if (q0) { int s2 = base + (int)__popcll(m0 & lt);
                  if (s2 < LDSCAP) sC[s2] = ((unsigned long long)k0 << 32) | (unsigned)(0x7FFFFFFF - p0); }
        if (q1) { int s2 = base + c0 + (int)__popcll(m1 & lt);
                  if (s2 < LDSCAP) sC[s2] = ((unsigned long long)k1 << 32) | (unsigned)(0x7FFFFFFF - (p0 + 512)); }
        if (q2) { int s2 = base + c0 + c1 + (int)__popcll(m2 & lt);
                  if (s2 < LDSCAP) sC[s2] = ((unsigned long long)k2 << 32) | (unsigned)(0x7FFFFFFF - (p0 + 1024)); }
        if (q3) { int s2 = base + c0 + c1 + c2 + (int)__popcll(m3 & lt);
                  if (s2 < LDSCAP) sC[s2] = ((unsigned long long)k3 << 32) | (unsigned)(0x7FFFFFFF - (p0 + 1536)); }
    }
    __syncthreads();

    // ---- Phase C: merge ----
    if (!sOver) {
        merge_rounds(sC, sB, sWin, sCnt, 0ull, t, wv, lane);
    } else {
        // exact fallback: re-gather in 24-sub chunks (<= 6144 each) with carry
        for (int lo = 0; lo < n; lo += CSUBS) {
            int lim = n < lo + CSUBS ? n : lo + CSUBS;
            if (t == 0) sCnt = 0;
            __syncthreads();
            for (int si = lo + wv; si < lim; si += 4) {
                int sub = sList[si];
                int tile = sub >> 3, sr = sub & 7;
                int xs = (tile & 7) << 6;
                int ys = ((tile >> 3) << 5) + (sr << 2);
                int p0 = (ys << 9) + xs + lane;
                unsigned k0 = kp[p0];
                unsigned k1 = kp[p0 + 512];
                unsigned k2 = kp[p0 + 1024];
                unsigned k3 = kp[p0 + 1536];
                bool q0 = k0 >= tv, q1 = k1 >= tv, q2 = k2 >= tv, q3 = k3 >= tv;
                unsigned long long m0 = __ballot(q0), m1 = __ballot(q1);
                unsigned long long m2 = __ballot(q2), m3 = __ballot(q3);
                int c0 = (int)__popcll(m0), c1 = (int)__popcll(m1);
                int c2 = (int)__popcll(m2), c3 = (int)__popcll(m3);
                int tot = c0 + c1 + c2 + c3;
                if (tot == 0) continue;
                int base = 0;
                if (lane == 0) base = atomicAdd(&sCnt, tot);
                base = __shfl(base, 0);
                if (q0) sC[base + (int)__popcll(m0 & lt)] =
                    ((unsigned long long)k0 << 32) | (unsigned)(0x7FFFFFFF - p0);
                if (q1) sC[base + c0 + (int)__popcll(m1 & lt)] =
                    ((unsigned long long)k1 << 32) | (unsigned)(0x7FFFFFFF - (p0 + 512));
                if (q2) sC[base + c0 + c1 + (int)__popcll(m2 & lt)] =
                    ((unsigned long long)k2 << 32) | (unsigned)(0x7FFFFFFF - (p0 + 1024));
                if (q3) sC[base + c0 + c1 + c2 + (int)__popcll(m3 & lt)] =
                    ((unsigned long long)k3 << 32) | (unsigned)(0x7FFFFFFF - (p0 + 1536));
            }
            __syncthreads();
            unsigned long long kc = (lo > 0 && t < K) ? sWin[t] : 0ull;
            __syncthreads();
            merge_rounds(sC, sB, sWin, sCnt, kc, t, wv, lane);
        }
    }

    // ---- epilogue ----
    if (t < K) sIdx[t] = 0x7FFFFFFF - (int)(unsigned)(sWin[t] & 0xFFFFFFFFull);
    __syncthreads();
    if (map == 0) {
        if (t < K) {
            int p = sIdx[t];
            float m = img[(((size_t)(b * NCH + 0)) << 18) + p];
            m = fmaxf(m, img[(((size_t)(b * NCH + 1)) << 18) + p]);
            m = fmaxf(m, img[(((size_t)(b * NCH + 2)) << 18) + p]);
            sM[t] = m;
        }
        __syncthreads();
        if (t == 0) {
            float bm = -FINF;
            int bj = 0;
            for (int j = 0; j < K; ++j)
                if (sM[j] > bm) { bm = sM[j]; bj = j; }   // strict > = first occurrence
            int p = sIdx[bj];
#pragma unroll
            for (int c = 0; c < NCH; ++c)
                A1[b * NCH + c] = img[(((size_t)(b * NCH + c)) << 18) + p];
        }
    } else {
        if (t < BATCH * NCH) {
            const float* xp = img + ((size_t)t << 18);
            float s = 0.0f;
            for (int j = 0; j < K; ++j) s += xp[sIdx[j]];
            atomicAdd(&A2sum[t], s);
        }
    }
}

__device__ __forceinline__ float tvh(unsigned h, bool hi, float r) {
    unsigned short s = hi ? (unsigned short)(h >> 16) : (unsigned short)(h & 0xFFFF);
    return fmaf(-h2f(s), r, r);
}

// ---------------------------------------------------------------------------
// K3 (r24-proven): t = 1 - 0.95 * min_c (1 - M_c)*r_c from the BLOCKED fp16
// Vmax layout (128 tiles x 256 records per channel): per thread one (tile,v)
// record = 2 rows x 4 cols; 3x16B loads, 2x16B stores. r_c inline.
__global__ __launch_bounds__(256) void final_t_kernel(
    const unsigned* __restrict__ vmaxb, const float* __restrict__ A1,
    const float* __restrict__ A2sum, float* __restrict__ out) {
    int g = blockIdx.x * 256 + threadIdx.x;   // 524288 threads
    int b = g >> 15;                           // 32768 records per batch
    int rem = g & 32767;
    int tile = rem >> 8;                       // 0..127
    int v = rem & 255;
    const float invBK = 1.0f / (float)BK;
    float A0 = 0.75f * A1[b * NCH + 0] + 0.25f * (A2sum[b * NCH + 0] * invBK);
    float Ab = 0.75f * A1[b * NCH + 1] + 0.25f * (A2sum[b * NCH + 1] * invBK);
    float Ac = 0.75f * A1[b * NCH + 2] + 0.25f * (A2sum[b * NCH + 2] * invBK);
    float r0 = 1.0f / ((1.0f - A0) + 1e-6f);
    float r1 = 1.0f / ((1.0f - Ab) + 1e-6f);
    float r2 = 1.0f / ((1.0f - Ac) + 1e-6f);
    size_t rbase = (size_t)tile * 1024 + v * 4;
    uint4 c0 = *(const uint4*)(vmaxb + (size_t)(b * NCH + 0) * VCH + rbase);
    uint4 c1 = *(const uint4*)(vmaxb + (size_t)(b * NCH + 1) * VCH + rbase);
    uint4 c2 = *(const uint4*)(vmaxb + (size_t)(b * NCH + 2) * VCH + rbase);
    float4 ta, tb;
    ta.x = 1.0f - 0.95f * fminf(fminf(tvh(c0.x, false, r0), tvh(c1.x, false, r1)), tvh(c2.x, false, r2));
    ta.y = 1.0f - 0.95f * fminf(fminf(tvh(c0.x, true, r0), tvh(c1.x, true, r1)), tvh(c2.x, true, r2));
    ta.z = 1.0f - 0.95f * fminf(fminf(tvh(c0.y, false, r0), tvh(c1.y, false, r1)), tvh(c2.y, false, r2));
    ta.w = 1.0f - 0.95f * fminf(fminf(tvh(c0.y, true, r0), tvh(c1.y, true, r1)), tvh(c2.y, true, r2));
    tb.x = 1.0f - 0.95f * fminf(fminf(tvh(c0.z, false, r0), tvh(c1.z, false, r1)), tvh(c2.z, false, r2));
    tb.y = 1.0f - 0.95f * fminf(fminf(tvh(c0.z, true, r0), tvh(c1.z, true, r1)), tvh(c2.z, true, r2));
    tb.z = 1.0f - 0.95f * fminf(fminf(tvh(c0.w, false, r0), tvh(c1.w, false, r1)), tvh(c2.w, false, r2));
    tb.w = 1.0f - 0.95f * fminf(fminf(tvh(c0.w, true, r0), tvh(c1.w, true, r1)), tvh(c2.w, true, r2));
    int tx0 = (tile & 7) << 6;
    int ty0 = (tile >> 3) << 5;
    int rg = v >> 4, cg = v & 15;
    int row0 = ty0 + (rg << 1);
    int col = tx0 + (cg << 2);
    float* op3 = out + (((size_t)(b * 4 + 3)) << 18);
    *(float4*)&op3[(row0 << 9) + col] = ta;
    *(float4*)&op3[((row0 + 1) << 9) + col] = tb;
}

// ---------------------------------------------------------------------------
extern "C" void kernel_launch(void* const* d_in, const int* in_sizes, int n_in,
                              void* d_out, int out_size, void* d_ws, size_t ws_size,
                              hipStream_t stream) {
    const float* x = (const float*)d_in[0];
    float* out = (float*)d_out;

    const size_t nPix = (size_t)BATCH * HW;      // 4,194,304

    unsigned* dcK = (unsigned*)d_ws;                             // 16 MB
    unsigned* bcK = dcK + nPix;                                  // 16 MB (contiguous with dcK)
    unsigned* vmaxb = bcK + nPix;                                // 24 MB blocked fp16 (u32 view)
    unsigned* subkey = vmaxb + (size_t)BATCH * NCH * VCH;        // [2][16][1024]
    float* A1 = (float*)(subkey + (size_t)NPAIR * NSUB);
    float* A2sum = A1 + BATCH * NCH;

    pool_maps_kernel<<<BATCH * 128, 512, 0, stream>>>(x, vmaxb, dcK, bcK, subkey, out, A2sum);
    select_kernel<<<NPAIR, 256, 0, stream>>>(dcK, subkey, x, A1, A2sum);
    final_t_kernel<<<2048, 256, 0, stream>>>(vmaxb, A1, A2sum, out);
}